// Round 8
// baseline (260.014 us; speedup 1.0000x reference)
//
#include <hip/hip_runtime.h>
#include <hip/hip_bf16.h>

typedef __attribute__((ext_vector_type(8))) __bf16 bf16x8;
typedef __attribute__((ext_vector_type(4))) float  f32x4;

#define SDIM 49
#define NDIM 1024
#define CDIM 384
#define DDIM 512
#define DMC  64
#define SCALE (1.0f/(SDIM*NDIM))
#define SLOT 65536   // A(keys) 32KB + B(q) 32KB per K-step slot; 2 slots = 128KB

__device__ __forceinline__ void gload16(const void* g, void* l) {
    __builtin_amdgcn_global_load_lds((const __attribute__((address_space(1))) void*)g,
                                     (__attribute__((address_space(3))) void*)l, 16, 0, 0);
}

// ---------------------------------------------------------------------------
// pack + passthrough copy fused from registers (no second global read).
// ---------------------------------------------------------------------------
__global__ __launch_bounds__(512) void pack_copy_kernel(
    const float* __restrict__ xloc, const float* __restrict__ mv,
    const float* __restrict__ cv,   __hip_bfloat16* __restrict__ dst,
    float* __restrict__ cpy)
{
    const int j = blockIdx.x;
    const int d = threadIdx.x;
    float vals[SDIM];
    if (d < CDIM) {
        const float* p = xloc + ((size_t)j * CDIM + d) * SDIM;
        #pragma unroll
        for (int s = 0; s < SDIM; ++s) vals[s] = p[s];
        float* dcp = cpy + ((size_t)j * CDIM + d) * SDIM;
        #pragma unroll
        for (int s = 0; s < SDIM; ++s) dcp[s] = vals[s];
    } else if (d < CDIM + DMC) {
        float v = mv[j * DMC + (d - CDIM)];
        #pragma unroll
        for (int s = 0; s < SDIM; ++s) vals[s] = v;
    } else {
        float v = cv[j * DMC + (d - CDIM - DMC)];
        #pragma unroll
        for (int s = 0; s < SDIM; ++s) vals[s] = v;
    }
    #pragma unroll
    for (int s = 0; s < SDIM; ++s)
        dst[((size_t)s * NDIM + j) * DDIM + d] = __float2bfloat16(vals[s]);
}

__global__ void fpack_kernel(const float* __restrict__ f,
                             __hip_bfloat16* __restrict__ dst, int n)
{
    int i = blockIdx.x * blockDim.x + threadIdx.x;
    if (i < n) dst[i] = __float2bfloat16(f[i]);
}

// ---------------------------------------------------------------------------
// PERSISTENT fused GEMM + partial-LSE.
// grid = 256 blocks of 512 (8 waves = 2 wk x 4 wq); block (xcd=bid&7, j=bid>>3)
// owns tiles g = 196*xcd + j + 32k (6-7 tiles, per-XCD contiguous -> L2 reuse).
// Tile g: s=g>>5, kb=(g>>3)&3, qb=g&7.  Tile: 256 keys x 256 q, BK=64.
// MFMA 16x16x32 bf16: acc[a=0..7][b=0..3]; C/D col=lane&15, row=(lane>>4)*4+reg.
// LDS slot: A rows [256][128B] @0, B @32K; content[row][col] =
// G[row][kstep*128 + (col ^ ((row&7)<<4))]; linear LDS dest + pre-swizzled
// global source (R4-R7: 0 bank conflicts).
// Continuous pipeline across tiles: at step t, P1/P2 issue the 8 stage loads
// for step t+1 (slot (t+1)&1; t=7 stages NEXT TILE's step 0).  P0 waits
// vmcnt(0) on loads issued >=2.5 phases earlier (no fresh-load drain).
// Phases: P0{vmcnt,bar} P1{stage4|12 reads|bar|lgkm|16 MFMA|bar}
// P2{stage4|4 reads|...} P3{8 reads|...} P4{16 MFMA} (no barrier).
// Epilogue per tile overlaps next tile's in-flight step-0 loads.
// ---------------------------------------------------------------------------
__global__ __launch_bounds__(512, 2) void loss_kernel(
    const __hip_bfloat16* __restrict__ Fm,   // [N,512]
    const __hip_bfloat16* __restrict__ Km,   // [S,N,512] keys
    const __hip_bfloat16* __restrict__ Qm,   // [S,N,512] queries (pred2)
    float2* __restrict__ part,               // [S*2048][8]
    float* __restrict__ out)
{
    extern __shared__ __attribute__((aligned(16))) char sm[];   // 2*SLOT

    const int bid = blockIdx.x;
    const int xcd = bid & 7;
    const int jj  = bid >> 3;
    const int g0  = 196 * xcd;
    const int gend = g0 + 196;

    const int tid  = threadIdx.x;
    const int lane = tid & 63;
    const int w    = tid >> 6;
    const int l15  = lane & 15;
    const int l4   = lane >> 4;   // 0..3
    const int wk   = w >> 2;      // 0..1 key half
    const int wq   = w & 3;       // 0..3 q quarter

    // staging: thread covers rows c*64 + (tid>>3), 16B col (tid&7)*16;
    // pre-swizzled source col = col ^ ((row&7)<<4)
    const int trow = tid >> 3;
    const int scol = (((tid & 7) ^ ((tid >> 3) & 7)) << 4);

    // compute-side addressing
    const unsigned xo   = (unsigned)((l15 & 7) << 4);
    const unsigned arow = (unsigned)((wk * 128 + l15) * 128);
    const unsigned brow = 32768u + (unsigned)((wq * 64 + l15) * 128);

    auto APtr = [&](int gg) -> const char* {
        const int s = gg >> 5, kb = (gg >> 3) & 3;
        return (const char*)Km + ((size_t)s * NDIM + (size_t)kb * 256) * 1024;
    };
    auto BPtr = [&](int gg) -> const char* {
        const int s = gg >> 5, qb = gg & 7;
        return (qb < 4)
            ? ((const char*)Fm + (size_t)qb * 256 * 1024)
            : ((const char*)Qm + ((size_t)s * NDIM + (size_t)(qb - 4) * 256) * 1024);
    };
    auto stage4 = [&](const char* A, const char* B, int ko, char* slot, int h) {
        #pragma unroll
        for (int c = 2 * h; c < 2 * h + 2; ++c) {
            gload16(A + (size_t)(c * 64 + trow) * 1024 + ko + scol,
                    slot + c * 8192 + tid * 16);
            gload16(B + (size_t)(c * 64 + trow) * 1024 + ko + scol,
                    slot + 32768 + c * 8192 + tid * 16);
        }
    };

    f32x4 acc[8][4];
    bf16x8 afr[4][2], bfr[4][2];

    #define READ_A(H) do {                                                    \
        _Pragma("unroll")                                                     \
        for (int a = 0; a < 4; ++a)                                           \
            _Pragma("unroll")                                                 \
            for (int kc = 0; kc < 2; ++kc)                                    \
                afr[a][kc] = *(const bf16x8*)(sb_ + arow + (H) * 8192u        \
                    + a * 2048u + (((unsigned)(kc * 64 + l4 * 16)) ^ xo));    \
    } while (0)

    #define READ_B(H) do {                                                    \
        _Pragma("unroll")                                                     \
        for (int b = 0; b < 2; ++b)                                           \
            _Pragma("unroll")                                                 \
            for (int kc = 0; kc < 2; ++kc)                                    \
                bfr[(H)*2 + b][kc] = *(const bf16x8*)(sb_ + brow              \
                    + ((H)*2 + b) * 2048u                                     \
                    + (((unsigned)(kc * 64 + l4 * 16)) ^ xo));                \
    } while (0)

    #define MFMA_Q(AH, BH) do {                                               \
        _Pragma("unroll")                                                     \
        for (int a = 0; a < 4; ++a)                                           \
            _Pragma("unroll")                                                 \
            for (int b = 0; b < 2; ++b)                                       \
                _Pragma("unroll")                                             \
                for (int kc = 0; kc < 2; ++kc)                                \
                    acc[(AH)*4 + a][(BH)*2 + b] =                             \
                        __builtin_amdgcn_mfma_f32_16x16x32_bf16(              \
                            afr[a][kc], bfr[(BH)*2 + b][kc],                  \
                            acc[(AH)*4 + a][(BH)*2 + b], 0, 0, 0);            \
    } while (0)

    // prologue: stage first tile's step 0 into slot 0
    {
        const char* A0 = APtr(g0 + jj);
        const char* B0 = BPtr(g0 + jj);
        stage4(A0, B0, 0, sm, 0);
        stage4(A0, B0, 0, sm, 1);
    }

    for (int g = g0 + jj; g < gend; g += 32) {
        const char* Ag = APtr(g);
        const char* Bg = BPtr(g);
        const bool hasNext = (g + 32) < gend;
        const char* An = hasNext ? APtr(g + 32) : Ag;
        const char* Bn = hasNext ? BPtr(g + 32) : Bg;

        #pragma unroll
        for (int a = 0; a < 8; ++a)
            #pragma unroll
            for (int b = 0; b < 4; ++b) acc[a][b] = f32x4{0.f, 0.f, 0.f, 0.f};

        #pragma unroll
        for (int t = 0; t < 8; ++t) {
            const char* sb_ = sm + (size_t)(t & 1) * SLOT;
            char* ns_ = sm + (size_t)((t + 1) & 1) * SLOT;
            const bool pf = (t < 7) || hasNext;
            const char* sA = (t < 7) ? Ag : An;
            const char* sB = (t < 7) ? Bg : Bn;
            const int ko = (t < 7) ? (t + 1) * 128 : 0;

            // ---- P0: slot-t loads are >=2.5 phases old -> near-free wait
            asm volatile("s_waitcnt vmcnt(0)" ::: "memory");
            __builtin_amdgcn_s_barrier();
            // ---- P1
            if (pf) stage4(sA, sB, ko, ns_, 0);
            READ_A(0); READ_B(0);
            __builtin_amdgcn_s_barrier();
            asm volatile("s_waitcnt lgkmcnt(0)" ::: "memory");
            __builtin_amdgcn_s_setprio(1); MFMA_Q(0, 0); __builtin_amdgcn_s_setprio(0);
            __builtin_amdgcn_s_barrier();
            // ---- P2
            if (pf) stage4(sA, sB, ko, ns_, 1);
            READ_B(1);
            __builtin_amdgcn_s_barrier();
            asm volatile("s_waitcnt lgkmcnt(0)" ::: "memory");
            __builtin_amdgcn_s_setprio(1); MFMA_Q(0, 1); __builtin_amdgcn_s_setprio(0);
            __builtin_amdgcn_s_barrier();
            // ---- P3
            READ_A(1);
            __builtin_amdgcn_s_barrier();
            asm volatile("s_waitcnt lgkmcnt(0)" ::: "memory");
            __builtin_amdgcn_s_setprio(1); MFMA_Q(1, 0); __builtin_amdgcn_s_setprio(0);
            __builtin_amdgcn_s_barrier();
            // ---- P4 (no reads; next P0's barrier closes the step)
            __builtin_amdgcn_s_setprio(1); MFMA_Q(1, 1); __builtin_amdgcn_s_setprio(0);
        }

        // ---- epilogue (overlaps next tile's in-flight step-0 loads)
        const int s  = g >> 5;
        const int kb = (g >> 3) & 3;
        const int qb = g & 7;

        float q_m[4], q_s[4];
        #pragma unroll
        for (int b = 0; b < 4; ++b) {
            float m = -3.0e38f;
            #pragma unroll
            for (int a = 0; a < 8; ++a)
                #pragma unroll
                for (int r = 0; r < 4; ++r) m = fmaxf(m, acc[a][b][r]);
            float ss = 0.0f;
            #pragma unroll
            for (int a = 0; a < 8; ++a)
                #pragma unroll
                for (int r = 0; r < 4; ++r) ss += __expf(acc[a][b][r] - m);
            #pragma unroll
            for (int off = 16; off <= 32; off <<= 1) {
                float mo = __shfl_xor(m, off, 64);
                float so = __shfl_xor(ss, off, 64);
                float nm = fmaxf(m, mo);
                ss = ss * __expf(m - nm) + so * __expf(mo - nm);
                m = nm;
            }
            q_m[b] = m; q_s[b] = ss;
        }
        if (lane < 16) {
            const size_t rowb = (size_t)s * 2048 + (size_t)qb * 256 + wq * 64 + lane;
            #pragma unroll
            for (int b = 0; b < 4; ++b)
                part[(rowb + b * 16) * 8 + kb * 2 + wk] = make_float2(q_m[b], q_s[b]);
        }

        if (kb == (qb & 3) && (wq >> 1) == wk) {
            float d = 0.0f;
            const bool lok = (((lane >> 2) & 3) == l4);
            if (wq & 1) {
                #pragma unroll
                for (int b = 0; b < 4; ++b)
                    #pragma unroll
                    for (int r = 0; r < 4; ++r)
                        if (lok && r == (lane & 3)) d += acc[4 + b][b][r];
            } else {
                #pragma unroll
                for (int b = 0; b < 4; ++b)
                    #pragma unroll
                    for (int r = 0; r < 4; ++r)
                        if (lok && r == (lane & 3)) d += acc[b][b][r];
            }
            #pragma unroll
            for (int off = 1; off < 64; off <<= 1) d += __shfl_xor(d, off, 64);
            if (lane == 0) atomicAdd(out, -d * SCALE);
        }
    }
    #undef READ_A
    #undef READ_B
    #undef MFMA_Q
}

// merge the 8 per-(kb,wk) partials of each row -> lse, accumulate loss
__global__ __launch_bounds__(256) void reduce_kernel(
    const float2* __restrict__ part, float* __restrict__ out)
{
    const int row = blockIdx.x * 256 + threadIdx.x;   // 392*256 = 100352 rows
    const float2* p = part + (size_t)row * 8;
    float m = -3.0e38f;
    float2 q[8];
    #pragma unroll
    for (int i = 0; i < 8; ++i) { q[i] = p[i]; m = fmaxf(m, q[i].x); }
    float ssum = 0.0f;
    #pragma unroll
    for (int i = 0; i < 8; ++i) ssum += q[i].y * __expf(q[i].x - m);
    float v = m + __logf(ssum);
    #pragma unroll
    for (int off = 1; off < 64; off <<= 1) v += __shfl_xor(v, off, 64);
    __shared__ float red[4];
    const int lane = threadIdx.x & 63, w = threadIdx.x >> 6;
    if (lane == 0) red[w] = v;
    __syncthreads();
    if (threadIdx.x == 0)
        atomicAdd(out, (red[0] + red[1] + red[2] + red[3]) * SCALE);
}

extern "C" void kernel_launch(void* const* d_in, const int* in_sizes, int n_in,
                              void* d_out, int out_size, void* d_ws, size_t ws_size,
                              hipStream_t stream)
{
    (void)in_sizes; (void)n_in; (void)out_size; (void)ws_size;
    const float* f  = (const float*)d_in[0];
    const float* x  = (const float*)d_in[1];
    const float* xp = (const float*)d_in[2];
    const float* mt = (const float*)d_in[3];
    const float* mp = (const float*)d_in[4];
    const float* ct = (const float*)d_in[5];
    const float* cp = (const float*)d_in[6];
    float* out = (float*)d_out;

    char* ws = (char*)d_ws;
    const size_t packBytes = (size_t)SDIM * NDIM * DDIM * 2;   // 51.4 MB
    __hip_bfloat16* Km = (__hip_bfloat16*)ws;
    __hip_bfloat16* Qm = (__hip_bfloat16*)(ws + packBytes);
    __hip_bfloat16* Fm = (__hip_bfloat16*)(ws + 2 * packBytes);
    float2* part = (float2*)(ws + 2 * packBytes + (size_t)NDIM * DDIM * 2);

    hipMemsetAsync(out, 0, sizeof(float), stream);

    const int sz = NDIM * CDIM * SDIM;
    pack_copy_kernel<<<NDIM, 512, 0, stream>>>(xp, mp, cp, Km, out + 1);
    pack_copy_kernel<<<NDIM, 512, 0, stream>>>(x,  mt, ct, Qm, out + 1 + sz);
    fpack_kernel<<<(NDIM * DDIM + 255) / 256, 256, 0, stream>>>(f, Fm, NDIM * DDIM);

    loss_kernel<<<256, 512, 2 * SLOT, stream>>>(Fm, Km, Qm, part, out);
    reduce_kernel<<<392, 256, 0, stream>>>(part, out);
}